// Round 3
// baseline (1433.080 us; speedup 1.0000x reference)
//
#include <hip/hip_runtime.h>
#include <stdint.h>

#define BATCH 4
#define CINCH 3
#define HIN 128
#define WIN 128
#define NN 4096      // 64*64 output nodes per batch
#define CF 64        // feature channels
#define KNN 7

// ---------------------------------------------------------------- helpers
__device__ __forceinline__ unsigned long long u64min(unsigned long long a,
                                                     unsigned long long b) {
    return a < b ? a : b;
}

// insert candidate k into ascending sorted 7-list (drops max); per-lane
__device__ __forceinline__ void insert7(unsigned long long* lst,
                                        unsigned long long k) {
    unsigned long long cur = k;
#pragma unroll
    for (int i = 0; i < KNN; ++i) {
        unsigned long long lo = u64min(lst[i], cur);
        unsigned long long hi = (lst[i] < cur) ? cur : lst[i];
        lst[i] = lo;
        cur = hi;
    }
}

// ------------------------------------------------ K1: conv3x3 s2 p1 -> y[B][N][C]
// (unchanged from round 1 — bitwise-identical y)
__global__ __launch_bounds__(256) void conv_kernel(
    const float* __restrict__ x, const float* __restrict__ w,
    const float* __restrict__ bias, float* __restrict__ y) {
    __shared__ float ws[CF * CINCH * 9];
    __shared__ float bs[CF];
    for (int i = threadIdx.x; i < CF * CINCH * 9; i += 256) ws[i] = w[i];
    if (threadIdx.x < CF) bs[threadIdx.x] = bias[threadIdx.x];
    __syncthreads();

    int gid = blockIdx.x * 256 + threadIdx.x;   // ((b*4096)+n)*64 + c
    int c = gid & 63;
    int n = (gid >> 6) & (NN - 1);
    int b = gid >> 18;
    int oh = n >> 6, ow = n & 63;
    const float* xb = x + (size_t)b * CINCH * HIN * WIN;
    float acc = bs[c];
#pragma unroll
    for (int cin = 0; cin < CINCH; ++cin) {
#pragma unroll
        for (int kh = 0; kh < 3; ++kh) {
            int ih = oh * 2 - 1 + kh;
            if (ih < 0 || ih >= HIN) continue;
#pragma unroll
            for (int kw = 0; kw < 3; ++kw) {
                int iw = ow * 2 - 1 + kw;
                if (iw < 0 || iw >= WIN) continue;
                acc += xb[(cin * HIN + ih) * WIN + iw] *
                       ws[(c * CINCH + cin) * 9 + kh * 3 + kw];
            }
        }
    }
    y[(size_t)gid] = acc;
}

// ------------------------------------------------ K2: sq[n] = sum_c y[n][c]^2
// (unchanged from round 1 — bitwise-identical sq)
__global__ __launch_bounds__(256) void sq_kernel(const float* __restrict__ y,
                                                 float* __restrict__ sq) {
    int n = blockIdx.x * 256 + threadIdx.x;   // 0..B*NN-1
    const float4* yr = (const float4*)(y + (size_t)n * CF);
    float s = 0.f;
#pragma unroll
    for (int i = 0; i < 16; ++i) {
        float4 v = yr[i];
        s += v.x * v.x;
        s += v.y * v.y;
        s += v.z * v.z;
        s += v.w * v.w;
    }
    sq[n] = s;
}

// ------------------------------------------------ K3: GEMM + per-lane top-7
// lane owns ONE row (A in 64 VGPRs); B columns via wave-uniform (scalar) loads.
// 512 blocks x 256 thr: block bid -> g = bid&1, rw = bid>>1 (row-wave 0..255);
// wave w covers col-split cs = g*4+w (512 cols). Per-lane top-7 lists, then
// in-block LDS merge of the 4 waves -> part7[g][rw][7][64].
__global__ __launch_bounds__(256, 2) void gemm_select_kernel(
    const float* __restrict__ y, const float* __restrict__ sq,
    unsigned long long* __restrict__ part7) {
    __shared__ unsigned long long mlds[3][KNN][64];

    const int bid = blockIdx.x;
    const int g = bid & 1, rw = bid >> 1;
    const int b = rw >> 6;
    const int tid = threadIdx.x, w = tid >> 6, lane = tid & 63;
    const int cs = g * 4 + w;
    const int row = ((rw & 63) << 6) + lane;          // row within batch
    const float* yb = y + (size_t)b * NN * CF;
    const float* sqb = sq + b * NN;

    // A row -> registers (16 float4 = 64 VGPR), one-time
    float4 A4[16];
    const float4* ar = (const float4*)(yb + (size_t)row * CF);
#pragma unroll
    for (int i = 0; i < 16; ++i) A4[i] = ar[i];
    const float sqr = sqb[row];

    unsigned long long lst[KNN];
#pragma unroll
    for (int i = 0; i < KNN; ++i) lst[i] = ~0ull;

    const int c0 = cs * 512;
    for (int ct = 0; ct < 128; ++ct) {                // 4 cols per iter
        const int cbase = c0 + ct * 4;
        const float4* b0 = (const float4*)(yb + (size_t)(cbase + 0) * CF);
        const float4* b1 = (const float4*)(yb + (size_t)(cbase + 1) * CF);
        const float4* b2 = (const float4*)(yb + (size_t)(cbase + 2) * CF);
        const float4* b3 = (const float4*)(yb + (size_t)(cbase + 3) * CF);
        float a0 = 0.f, a1 = 0.f, a2 = 0.f, a3 = 0.f;
#pragma unroll
        for (int k = 0; k < 16; ++k) {
            float4 av = A4[k];
            float4 q0 = b0[k], q1 = b1[k], q2 = b2[k], q3 = b3[k];
            // k-ascending x,y,z,w chain per column: bitwise == round-1
            a0 += av.x * q0.x; a0 += av.y * q0.y; a0 += av.z * q0.z; a0 += av.w * q0.w;
            a1 += av.x * q1.x; a1 += av.y * q1.y; a1 += av.z * q1.z; a1 += av.w * q1.w;
            a2 += av.x * q2.x; a2 += av.y * q2.y; a2 += av.z * q2.z; a2 += av.w * q2.w;
            a3 += av.x * q3.x; a3 += av.y * q3.y; a3 += av.z * q3.z; a3 += av.w * q3.w;
        }
        float4 sc = *(const float4*)(sqb + cbase);    // uniform
        float d0 = (sqr + sc.x) - 2.0f * a0;
        float d1 = (sqr + sc.y) - 2.0f * a1;
        float d2v = (sqr + sc.z) - 2.0f * a2;
        float d3 = (sqr + sc.w) - 2.0f * a3;
        float s0 = sqrtf(fmaxf(d0, 0.0f));
        float s1 = sqrtf(fmaxf(d1, 0.0f));
        float s2 = sqrtf(fmaxf(d2v, 0.0f));
        float s3 = sqrtf(fmaxf(d3, 0.0f));
        unsigned long long k0 = ((unsigned long long)__float_as_uint(s0) << 32) | (unsigned)(cbase + 0);
        unsigned long long k1 = ((unsigned long long)__float_as_uint(s1) << 32) | (unsigned)(cbase + 1);
        unsigned long long k2 = ((unsigned long long)__float_as_uint(s2) << 32) | (unsigned)(cbase + 2);
        unsigned long long k3 = ((unsigned long long)__float_as_uint(s3) << 32) | (unsigned)(cbase + 3);
        if (k0 < lst[KNN - 1]) insert7(lst, k0);
        if (k1 < lst[KNN - 1]) insert7(lst, k1);
        if (k2 < lst[KNN - 1]) insert7(lst, k2);
        if (k3 < lst[KNN - 1]) insert7(lst, k3);
    }

    // merge 4 waves' lists (same rows) -> wave 0
    if (w > 0) {
#pragma unroll
        for (int q = 0; q < KNN; ++q) mlds[w - 1][q][lane] = lst[q];
    }
    __syncthreads();
    if (w == 0) {
#pragma unroll
        for (int mw = 0; mw < 3; ++mw)
#pragma unroll
            for (int q = 0; q < KNN; ++q) {
                unsigned long long k = mlds[mw][q][lane];
                if (k < lst[KNN - 1]) insert7(lst, k);
            }
        unsigned long long* dst = part7 + (((size_t)g * 256 + rw) * KNN) * 64;
#pragma unroll
        for (int q = 0; q < KNN; ++q) dst[q * 64 + lane] = lst[q];
    }
}

// ------------------------------------------------ K4: final merge + adj write
// 256 blocks: block rw handles 64 rows; wave0 merges 2x7 keys/row -> idx;
// then all 4 waves stream the 0/1 rows (write-BW bound).
__global__ __launch_bounds__(256) void merge_write_kernel(
    const unsigned long long* __restrict__ part7, float* __restrict__ adj) {
    __shared__ unsigned idx_lds[64][8];
    const int rw = blockIdx.x;                        // 0..255
    const int b = rw >> 6;
    const int tid = threadIdx.x, w = tid >> 6, lane = tid & 63;

    if (w == 0) {
        unsigned long long lst[KNN];
        const unsigned long long* p0 = part7 + (((size_t)0 * 256 + rw) * KNN) * 64;
        const unsigned long long* p1 = part7 + (((size_t)1 * 256 + rw) * KNN) * 64;
#pragma unroll
        for (int q = 0; q < KNN; ++q) lst[q] = p0[q * 64 + lane];
#pragma unroll
        for (int q = 0; q < KNN; ++q) {
            unsigned long long k = p1[q * 64 + lane];
            if (k < lst[KNN - 1]) insert7(lst, k);
        }
#pragma unroll
        for (int q = 0; q < KNN; ++q)
            idx_lds[lane][q] = (unsigned)(lst[q] & 0xffffffffu);
    }
    __syncthreads();

    const int rowbase = (rw & 63) << 6;
#pragma unroll 1
    for (int rl = w * 16; rl < w * 16 + 16; ++rl) {
        unsigned i0 = idx_lds[rl][0], i1 = idx_lds[rl][1], i2 = idx_lds[rl][2],
                 i3 = idx_lds[rl][3], i4 = idx_lds[rl][4], i5 = idx_lds[rl][5],
                 i6 = idx_lds[rl][6];
        float4* dst = (float4*)(adj + ((size_t)b * NN + rowbase + rl) * NN);
#pragma unroll 4
        for (int j = 0; j < 16; ++j) {
            int f4 = lane + j * 64;
            unsigned e = (unsigned)f4 * 4u;
            float vx = 0.f, vy = 0.f, vz = 0.f, vw = 0.f;
#define CHK(ii) { unsigned d = (ii) - e; \
                  vx = (d == 0u) ? 1.f : vx; vy = (d == 1u) ? 1.f : vy; \
                  vz = (d == 2u) ? 1.f : vz; vw = (d == 3u) ? 1.f : vw; }
            CHK(i0) CHK(i1) CHK(i2) CHK(i3) CHK(i4) CHK(i5) CHK(i6)
#undef CHK
            dst[f4] = make_float4(vx, vy, vz, vw);
        }
    }
}

// ------------------------------------------------ launcher
extern "C" void kernel_launch(void* const* d_in, const int* in_sizes, int n_in,
                              void* d_out, int out_size, void* d_ws, size_t ws_size,
                              hipStream_t stream) {
    const float* x = (const float*)d_in[0];
    const float* w = (const float*)d_in[1];
    const float* bias = (const float*)d_in[2];

    float* y = (float*)d_out;                               // [4][4096][64]
    float* adj = (float*)d_out + (size_t)BATCH * NN * CF;   // [4][4096][4096]

    float* sq = (float*)d_ws;                               // 16384 f32 = 64 KB
    unsigned long long* part7 =
        (unsigned long long*)((char*)d_ws + 65536);         // 2*256*7*64*8 = 1.75 MB

    conv_kernel<<<4096, 256, 0, stream>>>(x, w, bias, y);
    sq_kernel<<<64, 256, 0, stream>>>(y, sq);
    gemm_select_kernel<<<512, 256, 0, stream>>>(y, sq, part7);
    merge_write_kernel<<<256, 256, 0, stream>>>(part7, adj);
}

// Round 4
// 414.445 us; speedup vs baseline: 3.4578x; 3.4578x over previous
//
#include <hip/hip_runtime.h>
#include <stdint.h>

#define BATCH 4
#define CINCH 3
#define HIN 128
#define WIN 128
#define NN 4096      // 64*64 output nodes per batch
#define CF 64        // feature channels
#define KNN 7

typedef unsigned short u16;
typedef unsigned long long u64;
typedef __attribute__((ext_vector_type(8))) short bf16x8;
typedef __attribute__((ext_vector_type(4))) float f32x4;
typedef __attribute__((ext_vector_type(8))) unsigned short ushort8;

// ---------------------------------------------------------------- helpers
__device__ __forceinline__ u64 u64min(u64 a, u64 b) { return a < b ? a : b; }

template <int M>
__device__ __forceinline__ void insertM(u64* lst, u64 k) {
    u64 cur = k;
#pragma unroll
    for (int i = 0; i < M; ++i) {
        u64 lo = u64min(lst[i], cur);
        u64 hi = (lst[i] < cur) ? cur : lst[i];
        lst[i] = lo;
        cur = hi;
    }
}

// ------------------------------------------------ K1: conv3x3 s2 p1 -> y[B][N][C]
// (unchanged from round 1 — bitwise-identical y)
__global__ __launch_bounds__(256) void conv_kernel(
    const float* __restrict__ x, const float* __restrict__ w,
    const float* __restrict__ bias, float* __restrict__ y) {
    __shared__ float ws[CF * CINCH * 9];
    __shared__ float bs[CF];
    for (int i = threadIdx.x; i < CF * CINCH * 9; i += 256) ws[i] = w[i];
    if (threadIdx.x < CF) bs[threadIdx.x] = bias[threadIdx.x];
    __syncthreads();

    int gid = blockIdx.x * 256 + threadIdx.x;   // ((b*4096)+n)*64 + c
    int c = gid & 63;
    int n = (gid >> 6) & (NN - 1);
    int b = gid >> 18;
    int oh = n >> 6, ow = n & 63;
    const float* xb = x + (size_t)b * CINCH * HIN * WIN;
    float acc = bs[c];
#pragma unroll
    for (int cin = 0; cin < CINCH; ++cin) {
#pragma unroll
        for (int kh = 0; kh < 3; ++kh) {
            int ih = oh * 2 - 1 + kh;
            if (ih < 0 || ih >= HIN) continue;
#pragma unroll
            for (int kw = 0; kw < 3; ++kw) {
                int iw = ow * 2 - 1 + kw;
                if (iw < 0 || iw >= WIN) continue;
                acc += xb[(cin * HIN + ih) * WIN + iw] *
                       ws[(c * CINCH + cin) * 9 + kh * 3 + kw];
            }
        }
    }
    y[(size_t)gid] = acc;
}

// ------------------------------------------------ K2: sq (exact chain) + bf16 quant
__global__ __launch_bounds__(256) void sq_quant_kernel(
    const float* __restrict__ y, float* __restrict__ sq, u16* __restrict__ ybf) {
    int n = blockIdx.x * 256 + threadIdx.x;   // node 0..B*NN-1
    const float4* yr = (const float4*)(y + (size_t)n * CF);
    ushort8* yb8 = (ushort8*)(ybf + (size_t)n * CF);
    float s = 0.f;
#pragma unroll
    for (int i = 0; i < 8; ++i) {
        float4 a = yr[i * 2], c = yr[i * 2 + 1];
        float vv[8] = {a.x, a.y, a.z, a.w, c.x, c.y, c.z, c.w};
        ushort8 hv;
#pragma unroll
        for (int j = 0; j < 8; ++j) {
            float f = vv[j];
            s += f * f;          // exact chain: ascending c, matches round-1 sq
            uint32_t u = __float_as_uint(f);
            hv[j] = (u16)((u + 0x7fffu + ((u >> 16) & 1u)) >> 16);   // RNE bf16
        }
        yb8[i] = hv;
    }
    sq[n] = s;
}

// ------------------------------------------------ K3: fused screen+rescore+write
// 512 blocks (4 batches x 128 row-tiles of 32 rows), 256 threads.
// MFMA screen: A-operand = col data, B-operand = row data =>
//   C "row" (g*4+reg) = col-local, C "col" (lane&15) = row-local. Each lane owns
//   rows {j*16+lc} (j=0,1) and sees cols {w*1024 + ct*16 + g*4 + reg}.
__global__ __launch_bounds__(256) void screen_kernel(
    const u16* __restrict__ ybf, const float* __restrict__ yf,
    const float* __restrict__ sq, float* __restrict__ adj) {
    __shared__ float sqs[NN];            // 16 KB: this batch's sq
    __shared__ u64 mlds[32][16][8];      // 32 KB: per-lane partial top-8 lists
    __shared__ unsigned cidx[32][32];    // 4 KB: candidate cols / final idx
    __shared__ u64 ckey[32][32];         // 8 KB: exact rescore keys

    const int bid = blockIdx.x;
    const int b = bid >> 7;
    const int r0 = (bid & 127) << 5;     // 32 rows per block
    const int tid = threadIdx.x, w = tid >> 6, lane = tid & 63;
    const int lc = lane & 15, g = lane >> 4;
    const size_t nb = (size_t)b * NN;

    // stage sq for the whole batch
#pragma unroll
    for (int p = 0; p < 4; ++p) {
        int i = p * 256 + tid;
        *(float4*)&sqs[i * 4] = *(const float4*)&sq[nb + i * 4];
    }

    // B-operand: this block's 32 rows (2 row-tiles), K=64 in 2 chunks
    bf16x8 rf[2][2];
    float sqr[2];
#pragma unroll
    for (int j = 0; j < 2; ++j) {
        int row = r0 + j * 16 + lc;
#pragma unroll
        for (int kb = 0; kb < 2; ++kb)
            rf[j][kb] = *(const bf16x8*)(ybf + (nb + row) * CF + kb * 32 + g * 8);
        sqr[j] = sq[nb + row];
    }

    u64 lst[2][8];
#pragma unroll
    for (int j = 0; j < 2; ++j)
#pragma unroll
        for (int q = 0; q < 8; ++q) lst[j][q] = ~0ull;

    __syncthreads();

    const f32x4 zro = {0.f, 0.f, 0.f, 0.f};
    const int c0 = w * 1024;
    for (int ct = 0; ct < 64; ++ct) {
        const int cbase = c0 + ct * 16;
        bf16x8 a0 = *(const bf16x8*)(ybf + (nb + cbase + lc) * CF + g * 8);
        bf16x8 a1 = *(const bf16x8*)(ybf + (nb + cbase + lc) * CF + 32 + g * 8);
        float4 sc = *(const float4*)&sqs[cbase + g * 4];
        float scv[4] = {sc.x, sc.y, sc.z, sc.w};
#pragma unroll
        for (int j = 0; j < 2; ++j) {
            f32x4 acc = __builtin_amdgcn_mfma_f32_16x16x32_bf16(a0, rf[j][0], zro, 0, 0, 0);
            acc = __builtin_amdgcn_mfma_f32_16x16x32_bf16(a1, rf[j][1], acc, 0, 0, 0);
#pragma unroll
            for (int r = 0; r < 4; ++r) {
                int col = cbase + g * 4 + r;
                float d2a = fmaxf((sqr[j] + scv[r]) - 2.f * acc[r], 0.f);
                u64 key = ((u64)__float_as_uint(d2a) << 32) | (unsigned)col;
                if (key < lst[j][7]) insertM<8>(lst[j], key);
            }
        }
    }

    // dump per-lane lists: row_local = j*16+lc, source = w*4+g
#pragma unroll
    for (int j = 0; j < 2; ++j)
#pragma unroll
        for (int q = 0; q < 8; ++q) mlds[j * 16 + lc][w * 4 + g][q] = lst[j][q];
    __syncthreads();

    // phase M: 4 threads per row, each merges 4 sources (32 keys) -> top-8
    if (tid < 128) {
        const int row = tid >> 2, s4 = tid & 3;
        u64 top8[8];
#pragma unroll
        for (int q = 0; q < 8; ++q) top8[q] = ~0ull;
#pragma unroll
        for (int s = 0; s < 4; ++s)
#pragma unroll
            for (int q = 0; q < 8; ++q) {
                u64 k = mlds[row][s4 * 4 + s][q];
                if (k < top8[7]) insertM<8>(top8, k);
            }
#pragma unroll
        for (int q = 0; q < 8; ++q)
            cidx[row][s4 * 8 + q] = (unsigned)(top8[q] & 0xffffffffu);
    }
    __syncthreads();

    // phase R: exact f32 rescore (trusted chain), 8 threads/row x 4 cands
    {
        const int row = tid >> 3, s = tid & 7;
        const float4* yr = (const float4*)(yf + (nb + r0 + row) * CF);
        const float sr = sqs[r0 + row];
#pragma unroll
        for (int j2 = 0; j2 < 4; ++j2) {
            const int q = s * 4 + j2;
            const unsigned col = cidx[row][q];
            const float4* yc = (const float4*)(yf + (nb + col) * CF);
            float a = 0.f;
#pragma unroll
            for (int k = 0; k < 16; ++k) {
                float4 av = yr[k], bv = yc[k];
                a += av.x * bv.x;
                a += av.y * bv.y;
                a += av.z * bv.z;
                a += av.w * bv.w;
            }
            float d2 = (sr + sqs[col]) - 2.0f * a;
            float dd = sqrtf(fmaxf(d2, 0.0f));
            ckey[row][q] = ((u64)__float_as_uint(dd) << 32) | col;
        }
    }
    __syncthreads();

    // phase F: exact top-7 of the 32 candidates
    if (tid < 32) {
        u64 t7[KNN];
#pragma unroll
        for (int q = 0; q < KNN; ++q) t7[q] = ~0ull;
#pragma unroll
        for (int q = 0; q < 32; ++q) {
            u64 k = ckey[tid][q];
            if (k < t7[KNN - 1]) insertM<KNN>(t7, k);
        }
#pragma unroll
        for (int q = 0; q < KNN; ++q)
            cidx[tid][q] = (unsigned)(t7[q] & 0xffffffffu);
    }
    __syncthreads();

    // phase W: stream adj rows (wave w -> rows w*8..w*8+7)
    for (int rr = 0; rr < 8; ++rr) {
        const int row = w * 8 + rr;
        unsigned i0 = cidx[row][0], i1 = cidx[row][1], i2 = cidx[row][2],
                 i3 = cidx[row][3], i4 = cidx[row][4], i5 = cidx[row][5],
                 i6 = cidx[row][6];
        float4* dst = (float4*)(adj + ((size_t)(nb + r0 + row)) * NN);
#pragma unroll 4
        for (int cc = 0; cc < 16; ++cc) {
            int f4 = lane + cc * 64;
            unsigned e = (unsigned)f4 * 4u;
            float vx = 0.f, vy = 0.f, vz = 0.f, vw = 0.f;
#define CHK(ii) { unsigned d = (ii) - e; \
                  vx = (d == 0u) ? 1.f : vx; vy = (d == 1u) ? 1.f : vy; \
                  vz = (d == 2u) ? 1.f : vz; vw = (d == 3u) ? 1.f : vw; }
            CHK(i0) CHK(i1) CHK(i2) CHK(i3) CHK(i4) CHK(i5) CHK(i6)
#undef CHK
            dst[f4] = make_float4(vx, vy, vz, vw);
        }
    }
}

// ------------------------------------------------ launcher
extern "C" void kernel_launch(void* const* d_in, const int* in_sizes, int n_in,
                              void* d_out, int out_size, void* d_ws, size_t ws_size,
                              hipStream_t stream) {
    const float* x = (const float*)d_in[0];
    const float* w = (const float*)d_in[1];
    const float* bias = (const float*)d_in[2];

    float* y = (float*)d_out;                               // [4][4096][64]
    float* adj = (float*)d_out + (size_t)BATCH * NN * CF;   // [4][4096][4096]

    float* sq = (float*)d_ws;                               // 16384 f32 = 64 KB
    u16* ybf = (u16*)((char*)d_ws + 65536);                 // 2 MB bf16 features

    conv_kernel<<<4096, 256, 0, stream>>>(x, w, bias, y);
    sq_quant_kernel<<<64, 256, 0, stream>>>(y, sq, ybf);
    screen_kernel<<<512, 256, 0, stream>>>(ybf, y, sq, adj);
}

// Round 5
// 162.950 us; speedup vs baseline: 8.7946x; 2.5434x over previous
//
#include <hip/hip_runtime.h>
#include <stdint.h>

#define BATCH 4
#define CINCH 3
#define HIN 128
#define WIN 128
#define NN 4096      // 64*64 output nodes per batch
#define CF 64        // feature channels
#define KNN 7

typedef unsigned short u16;
typedef unsigned u32;
typedef unsigned long long u64;
typedef __attribute__((ext_vector_type(8))) short bf16x8;
typedef __attribute__((ext_vector_type(4))) float f32x4;
typedef __attribute__((ext_vector_type(8))) unsigned short ushort8;

// ---------------------------------------------------------------- helpers
__device__ __forceinline__ u64 u64min(u64 a, u64 b) { return a < b ? a : b; }
__device__ __forceinline__ u32 u32min(u32 a, u32 b) { return a < b ? a : b; }

template <int M>
__device__ __forceinline__ void insertM64(u64* lst, u64 k) {
    u64 cur = k;
#pragma unroll
    for (int i = 0; i < M; ++i) {
        u64 lo = u64min(lst[i], cur);
        u64 hi = (lst[i] < cur) ? cur : lst[i];
        lst[i] = lo;
        cur = hi;
    }
}

template <int M>
__device__ __forceinline__ void insertM32(u32* lst, u32 k) {
    u32 cur = k;
#pragma unroll
    for (int i = 0; i < M; ++i) {
        u32 lo = u32min(lst[i], cur);
        u32 hi = (lst[i] < cur) ? cur : lst[i];
        lst[i] = lo;
        cur = hi;
    }
}

// ------------------------------------------------ K1: conv3x3 s2 p1 -> y[B][N][C]
// (unchanged — bitwise-identical y)
__global__ __launch_bounds__(256) void conv_kernel(
    const float* __restrict__ x, const float* __restrict__ w,
    const float* __restrict__ bias, float* __restrict__ y) {
    __shared__ float ws[CF * CINCH * 9];
    __shared__ float bs[CF];
    for (int i = threadIdx.x; i < CF * CINCH * 9; i += 256) ws[i] = w[i];
    if (threadIdx.x < CF) bs[threadIdx.x] = bias[threadIdx.x];
    __syncthreads();

    int gid = blockIdx.x * 256 + threadIdx.x;   // ((b*4096)+n)*64 + c
    int c = gid & 63;
    int n = (gid >> 6) & (NN - 1);
    int b = gid >> 18;
    int oh = n >> 6, ow = n & 63;
    const float* xb = x + (size_t)b * CINCH * HIN * WIN;
    float acc = bs[c];
#pragma unroll
    for (int cin = 0; cin < CINCH; ++cin) {
#pragma unroll
        for (int kh = 0; kh < 3; ++kh) {
            int ih = oh * 2 - 1 + kh;
            if (ih < 0 || ih >= HIN) continue;
#pragma unroll
            for (int kw = 0; kw < 3; ++kw) {
                int iw = ow * 2 - 1 + kw;
                if (iw < 0 || iw >= WIN) continue;
                acc += xb[(cin * HIN + ih) * WIN + iw] *
                       ws[(c * CINCH + cin) * 9 + kh * 3 + kw];
            }
        }
    }
    y[(size_t)gid] = acc;
}

// ------------------------------------------------ K2: sq (exact chain) + bf16 quant
__global__ __launch_bounds__(256) void sq_quant_kernel(
    const float* __restrict__ y, float* __restrict__ sq, u16* __restrict__ ybf) {
    int n = blockIdx.x * 256 + threadIdx.x;   // node 0..B*NN-1
    const float4* yr = (const float4*)(y + (size_t)n * CF);
    ushort8* yb8 = (ushort8*)(ybf + (size_t)n * CF);
    float s = 0.f;
#pragma unroll
    for (int i = 0; i < 8; ++i) {
        float4 a = yr[i * 2], c = yr[i * 2 + 1];
        float vv[8] = {a.x, a.y, a.z, a.w, c.x, c.y, c.z, c.w};
        ushort8 hv;
#pragma unroll
        for (int j = 0; j < 8; ++j) {
            float f = vv[j];
            s += f * f;          // exact ascending chain (trusted)
            uint32_t u = __float_as_uint(f);
            hv[j] = (u16)((u + 0x7fffu + ((u >> 16) & 1u)) >> 16);   // RNE bf16
        }
        yb8[i] = hv;
    }
    sq[n] = s;
}

// ------------------------------------------------ K3: screen + exact rescore -> idx
// 512 blocks (4 batches x 128 row-tiles of 32 rows), 256 threads.
// Hot loop: u32 keys = (d2a_bits & 0xFFFFFF00) | (ct<<2|r). Exact f32 rescore of
// 32 candidates/row reproduces the trusted selection bitwise.
__global__ __launch_bounds__(256, 3) void screen_kernel(
    const u16* __restrict__ ybf, const float* __restrict__ yf,
    const float* __restrict__ sq, u32* __restrict__ idxg) {
    __shared__ u32 mlds[32 * 129];       // 16.5 KB padded: [row][src*8+q]
    __shared__ u64 ckey[32][32];         // 8 KB exact rescore keys
    __shared__ u32 cidx[32][32];         // 4 KB candidate cols

    const int bid = blockIdx.x;
    const int b = bid >> 7;
    const int r0 = (bid & 127) << 5;     // 32 rows per block
    const int tid = threadIdx.x, w = tid >> 6, lane = tid & 63;
    const int lc = lane & 15, g = lane >> 4;
    const size_t nb = (size_t)b * NN;

    // B-operand: this block's 32 rows (2 row-tiles), K=64 in 2 chunks
    bf16x8 rf[2][2];
    float sqr[2];
#pragma unroll
    for (int j = 0; j < 2; ++j) {
        int row = r0 + j * 16 + lc;
#pragma unroll
        for (int kb = 0; kb < 2; ++kb)
            rf[j][kb] = *(const bf16x8*)(ybf + (nb + row) * CF + kb * 32 + g * 8);
        sqr[j] = sq[nb + row];
    }

    u32 lst[2][8];
#pragma unroll
    for (int j = 0; j < 2; ++j)
#pragma unroll
        for (int q = 0; q < 8; ++q) lst[j][q] = 0xFFFFFFFFu;

    const f32x4 zro = {0.f, 0.f, 0.f, 0.f};
    const int c0 = w * 1024;
    const size_t cb = (nb + c0 + lc) * CF + (size_t)g * 8;

    bf16x8 na0 = *(const bf16x8*)(ybf + cb);
    bf16x8 na1 = *(const bf16x8*)(ybf + cb + 32);
    for (int ct = 0; ct < 64; ++ct) {
        bf16x8 a0 = na0, a1 = na1;
        if (ct < 63) {
            size_t nxt = cb + (size_t)(ct + 1) * 16 * CF;
            na0 = *(const bf16x8*)(ybf + nxt);
            na1 = *(const bf16x8*)(ybf + nxt + 32);
        }
        const int cbase = c0 + ct * 16;
        float4 sc = *(const float4*)&sq[nb + cbase + g * 4];
        float scv[4] = {sc.x, sc.y, sc.z, sc.w};
#pragma unroll
        for (int j = 0; j < 2; ++j) {
            f32x4 acc = __builtin_amdgcn_mfma_f32_16x16x32_bf16(a0, rf[j][0], zro, 0, 0, 0);
            acc = __builtin_amdgcn_mfma_f32_16x16x32_bf16(a1, rf[j][1], acc, 0, 0, 0);
#pragma unroll
            for (int r = 0; r < 4; ++r) {
                float d2a = fmaxf((sqr[j] + scv[r]) - 2.f * acc[r], 0.f);
                u32 key = (__float_as_uint(d2a) & 0xFFFFFF00u) | (u32)(ct * 4 + r);
                if (key < lst[j][7]) insertM32<8>(lst[j], key);
            }
        }
    }

    // dump per-lane lists: row = j*16+lc, src = w*4+g  (2-way max conflicts)
#pragma unroll
    for (int j = 0; j < 2; ++j)
#pragma unroll
        for (int q = 0; q < 8; ++q)
            mlds[(j * 16 + lc) * 129 + (w * 4 + g) * 8 + q] = lst[j][q];
    __syncthreads();

    // phase M: 4 threads/row, each merges 4 sources -> top-8 (exact-trunc + col order)
    if (tid < 128) {
        const int row = tid >> 2, s4 = tid & 3;
        u64 top8[8];
#pragma unroll
        for (int q = 0; q < 8; ++q) top8[q] = ~0ull;
#pragma unroll
        for (int s = 0; s < 4; ++s) {
            const int src = s4 * 4 + s;
            const u32 colhi = (src >> 2) * 1024 + (src & 3) * 4;
#pragma unroll
            for (int q = 0; q < 8; ++q) {
                u32 k = mlds[row * 129 + src * 8 + q];
                u32 idx8 = k & 0xFFu;
                u32 col = colhi + (idx8 >> 2) * 16 + (idx8 & 3);
                u64 mk = ((u64)(k & 0xFFFFFF00u) << 24) | col;
                if (mk < top8[7]) insertM64<8>(top8, mk);
            }
        }
#pragma unroll
        for (int q = 0; q < 8; ++q)
            cidx[row][s4 * 8 + q] = (u32)(top8[q] & 0xFFFu);
    }
    __syncthreads();

    // phase R: exact f32 rescore (trusted chain), 8 threads/row x 4 cands
    {
        const int row = tid >> 3, s = tid & 7;
        const float4* yr = (const float4*)(yf + (nb + r0 + row) * CF);
        const float sr = sq[nb + r0 + row];
#pragma unroll
        for (int j2 = 0; j2 < 4; ++j2) {
            const int q = s * 4 + j2;
            const u32 col = cidx[row][q];
            const float4* yc = (const float4*)(yf + (nb + col) * CF);
            float a = 0.f;
#pragma unroll
            for (int k = 0; k < 16; ++k) {
                float4 av = yr[k], bv = yc[k];
                a += av.x * bv.x;
                a += av.y * bv.y;
                a += av.z * bv.z;
                a += av.w * bv.w;
            }
            float d2 = (sr + sq[nb + col]) - 2.0f * a;
            float dd = sqrtf(fmaxf(d2, 0.0f));
            ckey[row][q] = ((u64)__float_as_uint(dd) << 32) | col;
        }
    }
    __syncthreads();

    // phase F: exact top-7 of 32 candidates -> global idx
    if (tid < 32) {
        u64 t7[KNN];
#pragma unroll
        for (int q = 0; q < KNN; ++q) t7[q] = ~0ull;
#pragma unroll
        for (int q = 0; q < 32; ++q) {
            u64 k = ckey[tid][q];
            if (k < t7[KNN - 1]) insertM64<KNN>(t7, k);
        }
        u32* dst = idxg + (nb + r0 + tid) * 8;
#pragma unroll
        for (int q = 0; q < KNN; ++q) dst[q] = (u32)(t7[q] & 0xFFFFFFFFu);
    }
}

// ------------------------------------------------ K4: zero-fill adj (BW floor)
__global__ __launch_bounds__(256) void fill_zero_kernel(float4* __restrict__ adj4) {
    size_t i = (size_t)blockIdx.x * 256 + threadIdx.x;
    const size_t stride = (size_t)2048 * 256;
    const float4 z = make_float4(0.f, 0.f, 0.f, 0.f);
#pragma unroll
    for (int it = 0; it < 32; ++it) adj4[i + (size_t)it * stride] = z;
}

// ------------------------------------------------ K5: scatter the 7 ones per row
__global__ __launch_bounds__(256) void scatter_kernel(const u32* __restrict__ idxg,
                                                      float* __restrict__ adj) {
    int gid = blockIdx.x * 256 + threadIdx.x;   // 0..131071
    int grow = gid >> 3, q = gid & 7;
    if (q < KNN) {
        u32 col = idxg[gid];
        adj[(size_t)grow * NN + col] = 1.0f;
    }
}

// ------------------------------------------------ launcher
extern "C" void kernel_launch(void* const* d_in, const int* in_sizes, int n_in,
                              void* d_out, int out_size, void* d_ws, size_t ws_size,
                              hipStream_t stream) {
    const float* x = (const float*)d_in[0];
    const float* w = (const float*)d_in[1];
    const float* bias = (const float*)d_in[2];

    float* y = (float*)d_out;                               // [4][4096][64]
    float* adj = (float*)d_out + (size_t)BATCH * NN * CF;   // [4][4096][4096]

    float* sq = (float*)d_ws;                               // 64 KB
    u16* ybf = (u16*)((char*)d_ws + 65536);                 // 2 MB bf16 features
    u32* idxg = (u32*)((char*)d_ws + 65536 + 2097152);      // 512 KB: idx[16384][8]

    conv_kernel<<<4096, 256, 0, stream>>>(x, w, bias, y);
    sq_quant_kernel<<<64, 256, 0, stream>>>(y, sq, ybf);
    screen_kernel<<<512, 256, 0, stream>>>(ybf, y, sq, idxg);
    fill_zero_kernel<<<2048, 256, 0, stream>>>((float4*)adj);
    scatter_kernel<<<512, 256, 0, stream>>>(idxg, adj);
}

// Round 6
// 155.645 us; speedup vs baseline: 9.2073x; 1.0469x over previous
//
#include <hip/hip_runtime.h>
#include <stdint.h>

#define BATCH 4
#define CINCH 3
#define HIN 128
#define WIN 128
#define NN 4096      // 64*64 output nodes per batch
#define CF 64        // feature channels
#define KNN 7

typedef unsigned short u16;
typedef unsigned u32;
typedef unsigned long long u64;
typedef __attribute__((ext_vector_type(8))) short bf16x8;
typedef __attribute__((ext_vector_type(4))) float f32x4;
typedef __attribute__((ext_vector_type(8))) unsigned short ushort8;

// ---------------------------------------------------------------- helpers
__device__ __forceinline__ u64 u64min(u64 a, u64 b) { return a < b ? a : b; }
__device__ __forceinline__ u32 u32min(u32 a, u32 b) { return a < b ? a : b; }

template <int M>
__device__ __forceinline__ void insertM64(u64* lst, u64 k) {
    u64 cur = k;
#pragma unroll
    for (int i = 0; i < M; ++i) {
        u64 lo = u64min(lst[i], cur);
        u64 hi = (lst[i] < cur) ? cur : lst[i];
        lst[i] = lo;
        cur = hi;
    }
}

template <int M>
__device__ __forceinline__ void insertM32(u32* lst, u32 k) {
    u32 cur = k;
#pragma unroll
    for (int i = 0; i < M; ++i) {
        u32 lo = u32min(lst[i], cur);
        u32 hi = (lst[i] < cur) ? cur : lst[i];
        lst[i] = lo;
        cur = hi;
    }
}

// ------------------------------------------------ K1: conv3x3 s2 p1 -> y[B][N][C]
// (unchanged — bitwise-identical y)
__global__ __launch_bounds__(256) void conv_kernel(
    const float* __restrict__ x, const float* __restrict__ w,
    const float* __restrict__ bias, float* __restrict__ y) {
    __shared__ float ws[CF * CINCH * 9];
    __shared__ float bs[CF];
    for (int i = threadIdx.x; i < CF * CINCH * 9; i += 256) ws[i] = w[i];
    if (threadIdx.x < CF) bs[threadIdx.x] = bias[threadIdx.x];
    __syncthreads();

    int gid = blockIdx.x * 256 + threadIdx.x;   // ((b*4096)+n)*64 + c
    int c = gid & 63;
    int n = (gid >> 6) & (NN - 1);
    int b = gid >> 18;
    int oh = n >> 6, ow = n & 63;
    const float* xb = x + (size_t)b * CINCH * HIN * WIN;
    float acc = bs[c];
#pragma unroll
    for (int cin = 0; cin < CINCH; ++cin) {
#pragma unroll
        for (int kh = 0; kh < 3; ++kh) {
            int ih = oh * 2 - 1 + kh;
            if (ih < 0 || ih >= HIN) continue;
#pragma unroll
            for (int kw = 0; kw < 3; ++kw) {
                int iw = ow * 2 - 1 + kw;
                if (iw < 0 || iw >= WIN) continue;
                acc += xb[(cin * HIN + ih) * WIN + iw] *
                       ws[(c * CINCH + cin) * 9 + kh * 3 + kw];
            }
        }
    }
    y[(size_t)gid] = acc;
}

// ------------------------------------------------ K2: sq (exact chain) + bf16 quant
__global__ __launch_bounds__(256) void sq_quant_kernel(
    const float* __restrict__ y, float* __restrict__ sq, u16* __restrict__ ybf) {
    int n = blockIdx.x * 256 + threadIdx.x;   // node 0..B*NN-1
    const float4* yr = (const float4*)(y + (size_t)n * CF);
    ushort8* yb8 = (ushort8*)(ybf + (size_t)n * CF);
    float s = 0.f;
#pragma unroll
    for (int i = 0; i < 8; ++i) {
        float4 a = yr[i * 2], c = yr[i * 2 + 1];
        float vv[8] = {a.x, a.y, a.z, a.w, c.x, c.y, c.z, c.w};
        ushort8 hv;
#pragma unroll
        for (int j = 0; j < 8; ++j) {
            float f = vv[j];
            s += f * f;          // exact ascending chain (trusted)
            uint32_t u = __float_as_uint(f);
            hv[j] = (u16)((u + 0x7fffu + ((u >> 16) & 1u)) >> 16);   // RNE bf16
        }
        yb8[i] = hv;
    }
    sq[n] = s;
}

// ------------------------------------------------ K3: screen + rescore + adj write
// 1024 blocks (4 batches x 256 row-tiles of 16 rows), 256 threads, 4 blocks/CU.
// Screen streams/keys/merge/rescore bitwise-identical to the R5-passing kernel.
// Tail: block zero-fills its own 16 adj rows (coalesced float4) then writes the
// 7 ones into L2-hot lines.
__global__ __launch_bounds__(256, 4) void screen_kernel(
    const u16* __restrict__ ybf, const float* __restrict__ yf,
    const float* __restrict__ sq, float* __restrict__ adj) {
    __shared__ u32 mlds[16 * 129];       // 8.25 KB padded: [row][src*8+q]
    __shared__ u64 ckey[16][32];         // 4 KB exact rescore keys
    __shared__ u32 cidx[16][32];         // 2 KB candidate cols / final idx

    const int bid = blockIdx.x;
    const int b = bid >> 8;
    const int r0 = (bid & 255) << 4;     // 16 rows per block
    const int tid = threadIdx.x, w = tid >> 6, lane = tid & 63;
    const int lc = lane & 15, g = lane >> 4;
    const size_t nb = (size_t)b * NN;

    // B-operand: this block's 16 rows, K=64 in 2 chunks
    const int row = r0 + lc;
    bf16x8 rf0 = *(const bf16x8*)(ybf + (nb + row) * CF + g * 8);
    bf16x8 rf1 = *(const bf16x8*)(ybf + (nb + row) * CF + 32 + g * 8);
    const float sqr = sq[nb + row];

    u32 lst[8];
#pragma unroll
    for (int q = 0; q < 8; ++q) lst[q] = 0xFFFFFFFFu;

    const f32x4 zro = {0.f, 0.f, 0.f, 0.f};
    const int c0 = w * 1024;
    const size_t cb = (nb + c0 + lc) * CF + (size_t)g * 8;

    bf16x8 na0 = *(const bf16x8*)(ybf + cb);
    bf16x8 na1 = *(const bf16x8*)(ybf + cb + 32);
    for (int ct = 0; ct < 64; ++ct) {
        bf16x8 a0 = na0, a1 = na1;
        if (ct < 63) {
            size_t nxt = cb + (size_t)(ct + 1) * 16 * CF;
            na0 = *(const bf16x8*)(ybf + nxt);
            na1 = *(const bf16x8*)(ybf + nxt + 32);
        }
        const int cbase = c0 + ct * 16;
        float4 sc = *(const float4*)&sq[nb + cbase + g * 4];
        float scv[4] = {sc.x, sc.y, sc.z, sc.w};
        f32x4 acc = __builtin_amdgcn_mfma_f32_16x16x32_bf16(a0, rf0, zro, 0, 0, 0);
        acc = __builtin_amdgcn_mfma_f32_16x16x32_bf16(a1, rf1, acc, 0, 0, 0);
#pragma unroll
        for (int r = 0; r < 4; ++r) {
            float d2a = fmaxf((sqr + scv[r]) - 2.f * acc[r], 0.f);
            u32 key = (__float_as_uint(d2a) & 0xFFFFFF00u) | (u32)(ct * 4 + r);
            if (key < lst[7]) insertM32<8>(lst, key);
        }
    }

    // dump per-lane lists: row = lc, src = w*4+g
#pragma unroll
    for (int q = 0; q < 8; ++q)
        mlds[lc * 129 + (w * 4 + g) * 8 + q] = lst[q];
    __syncthreads();

    // phase M: 4 threads/row, each merges 4 sources -> top-8 (trunc-key + col order)
    if (tid < 64) {
        const int mrow = tid >> 2, s4 = tid & 3;
        u64 top8[8];
#pragma unroll
        for (int q = 0; q < 8; ++q) top8[q] = ~0ull;
#pragma unroll
        for (int s = 0; s < 4; ++s) {
            const int src = s4 * 4 + s;
            const u32 colhi = (src >> 2) * 1024 + (src & 3) * 4;
#pragma unroll
            for (int q = 0; q < 8; ++q) {
                u32 k = mlds[mrow * 129 + src * 8 + q];
                u32 idx8 = k & 0xFFu;
                u32 col = colhi + (idx8 >> 2) * 16 + (idx8 & 3);
                u64 mk = ((u64)(k & 0xFFFFFF00u) << 24) | col;
                if (mk < top8[7]) insertM64<8>(top8, mk);
            }
        }
#pragma unroll
        for (int q = 0; q < 8; ++q)
            cidx[mrow][s4 * 8 + q] = (u32)(top8[q] & 0xFFFu);
    }
    __syncthreads();

    // phase R: exact f32 rescore (trusted chain), 16 threads/row x 2 cands
    {
        const int rrow = tid >> 4, s = tid & 15;
        const float4* yr = (const float4*)(yf + (nb + r0 + rrow) * CF);
        const float sr = sq[nb + r0 + rrow];
#pragma unroll
        for (int j2 = 0; j2 < 2; ++j2) {
            const int q = s * 2 + j2;
            const u32 col = cidx[rrow][q];
            const float4* yc = (const float4*)(yf + (nb + col) * CF);
            float a = 0.f;
#pragma unroll
            for (int k = 0; k < 16; ++k) {
                float4 av = yr[k], bv = yc[k];
                a += av.x * bv.x;
                a += av.y * bv.y;
                a += av.z * bv.z;
                a += av.w * bv.w;
            }
            float d2 = (sr + sq[nb + col]) - 2.0f * a;
            float dd = sqrtf(fmaxf(d2, 0.0f));
            ckey[rrow][q] = ((u64)__float_as_uint(dd) << 32) | col;
        }
    }
    __syncthreads();

    // phase F: exact top-7 of 32 candidates -> cidx[row][0..6]
    if (tid < 16) {
        u64 t7[KNN];
#pragma unroll
        for (int q = 0; q < KNN; ++q) t7[q] = ~0ull;
#pragma unroll
        for (int q = 0; q < 32; ++q) {
            u64 k = ckey[tid][q];
            if (k < t7[KNN - 1]) insertM64<KNN>(t7, k);
        }
#pragma unroll
        for (int q = 0; q < KNN; ++q)
            cidx[tid][q] = (u32)(t7[q] & 0xFFFFFFFFu);
    }
    __syncthreads();

    // phase Z: zero-fill this block's 16 adj rows (coalesced float4 stream)
    float4* dst = (float4*)(adj + (nb + r0) * NN);
    const float4 z = make_float4(0.f, 0.f, 0.f, 0.f);
#pragma unroll 8
    for (int k = 0; k < 64; ++k) dst[k * 256 + tid] = z;
    __syncthreads();

    // phase O: 7 ones per row into L2-hot lines
    if (tid < 16 * KNN) {
        const int orow = tid / KNN, q = tid % KNN;
        u32 col = cidx[orow][q];
        adj[(nb + r0 + orow) * NN + col] = 1.0f;
    }
}

// ------------------------------------------------ launcher
extern "C" void kernel_launch(void* const* d_in, const int* in_sizes, int n_in,
                              void* d_out, int out_size, void* d_ws, size_t ws_size,
                              hipStream_t stream) {
    const float* x = (const float*)d_in[0];
    const float* w = (const float*)d_in[1];
    const float* bias = (const float*)d_in[2];

    float* y = (float*)d_out;                               // [4][4096][64]
    float* adj = (float*)d_out + (size_t)BATCH * NN * CF;   // [4][4096][4096]

    float* sq = (float*)d_ws;                               // 64 KB
    u16* ybf = (u16*)((char*)d_ws + 65536);                 // 2 MB bf16 features

    conv_kernel<<<4096, 256, 0, stream>>>(x, w, bias, y);
    sq_quant_kernel<<<64, 256, 0, stream>>>(y, sq, ybf);
    screen_kernel<<<1024, 256, 0, stream>>>(ybf, y, sq, adj);
}

// Round 7
// 149.152 us; speedup vs baseline: 9.6082x; 1.0435x over previous
//
#include <hip/hip_runtime.h>
#include <stdint.h>

#define BATCH 4
#define CINCH 3
#define HIN 128
#define WIN 128
#define NN 4096      // 64*64 output nodes per batch
#define CF 64        // feature channels
#define KNN 7

typedef unsigned short u16;
typedef unsigned u32;
typedef unsigned long long u64;
typedef __attribute__((ext_vector_type(8))) short bf16x8;
typedef __attribute__((ext_vector_type(4))) float f32x4;

// ---------------------------------------------------------------- helpers
__device__ __forceinline__ u64 u64min(u64 a, u64 b) { return a < b ? a : b; }
__device__ __forceinline__ u32 u32min(u32 a, u32 b) { return a < b ? a : b; }

template <int M>
__device__ __forceinline__ void insertM64(u64* lst, u64 k) {
    u64 cur = k;
#pragma unroll
    for (int i = 0; i < M; ++i) {
        u64 lo = u64min(lst[i], cur);
        u64 hi = (lst[i] < cur) ? cur : lst[i];
        lst[i] = lo;
        cur = hi;
    }
}

template <int M>
__device__ __forceinline__ void insertM32(u32* lst, u32 k) {
    u32 cur = k;
#pragma unroll
    for (int i = 0; i < M; ++i) {
        u32 lo = u32min(lst[i], cur);
        u32 hi = (lst[i] < cur) ? cur : lst[i];
        lst[i] = lo;
        cur = hi;
    }
}

// ------------------------------------------------ K1: conv + sq + bf16 quant + adj zero-fill
// One wave = one node (c == lane). Each block also writes a contiguous 64 KB
// zero slice of adj (the 268 MB write rides on this latency-bound kernel's
// otherwise-idle HBM). acc chain bitwise-identical to prior rounds.
__global__ __launch_bounds__(256) void conv_fused_kernel(
    const float* __restrict__ x, const float* __restrict__ w,
    const float* __restrict__ bias, float* __restrict__ y,
    u16* __restrict__ ybf, float* __restrict__ sq, float4* __restrict__ adj4) {
    __shared__ float ws[CF * CINCH * 9];
    __shared__ float bs[CF];
    for (int i = threadIdx.x; i < CF * CINCH * 9; i += 256) ws[i] = w[i];
    if (threadIdx.x < CF) bs[threadIdx.x] = bias[threadIdx.x];

    // zero slice: 16 float4/thread, contiguous 64 KB per block
    {
        float4* dst = adj4 + (size_t)blockIdx.x * 4096;
        const float4 z = make_float4(0.f, 0.f, 0.f, 0.f);
#pragma unroll
        for (int k = 0; k < 16; ++k) dst[k * 256 + threadIdx.x] = z;
    }
    __syncthreads();

    int gid = blockIdx.x * 256 + threadIdx.x;   // ((b*4096)+n)*64 + c
    int c = gid & 63;                            // == lane
    int n = (gid >> 6) & (NN - 1);
    int b = gid >> 18;
    int oh = n >> 6, ow = n & 63;
    const float* xb = x + (size_t)b * CINCH * HIN * WIN;
    float acc = bs[c];
#pragma unroll
    for (int cin = 0; cin < CINCH; ++cin) {
#pragma unroll
        for (int kh = 0; kh < 3; ++kh) {
            int ih = oh * 2 - 1 + kh;
            if (ih < 0 || ih >= HIN) continue;
#pragma unroll
            for (int kw = 0; kw < 3; ++kw) {
                int iw = ow * 2 - 1 + kw;
                if (iw < 0 || iw >= WIN) continue;
                acc += xb[(cin * HIN + ih) * WIN + iw] *
                       ws[(c * CINCH + cin) * 9 + kh * 3 + kw];
            }
        }
    }
    y[(size_t)gid] = acc;

    // bf16 RNE quant (same formula as prior rounds)
    uint32_t u = __float_as_uint(acc);
    ybf[(size_t)gid] = (u16)((u + 0x7fffu + ((u >> 16) & 1u)) >> 16);

    // sq: wave tree-reduce of acc^2 (c == lane spans the channel dim)
    float s = acc * acc;
#pragma unroll
    for (int off = 32; off; off >>= 1) s += __shfl_xor(s, off, 64);
    if (c == 0) sq[gid >> 6] = s;
}

// ------------------------------------------------ K2: screen + rescore + ones
// 1024 blocks (4 batches x 256 row-tiles of 16 rows), 256 threads, 4 blocks/CU.
// Selection pipeline bitwise-identical to the R6-passing kernel; adj zeros are
// pre-written by K1, so only the 7 ones/row are stored here.
__global__ __launch_bounds__(256, 4) void screen_kernel(
    const u16* __restrict__ ybf, const float* __restrict__ yf,
    const float* __restrict__ sq, float* __restrict__ adj) {
    __shared__ u32 mlds[16 * 129];       // 8.25 KB padded: [row][src*8+q]
    __shared__ u64 ckey[16][32];         // 4 KB exact rescore keys
    __shared__ u32 cidx[16][32];         // 2 KB candidate cols / final idx

    const int bid = blockIdx.x;
    const int b = bid >> 8;
    const int r0 = (bid & 255) << 4;     // 16 rows per block
    const int tid = threadIdx.x, w = tid >> 6, lane = tid & 63;
    const int lc = lane & 15, g = lane >> 4;
    const size_t nb = (size_t)b * NN;

    // B-operand: this block's 16 rows, K=64 in 2 chunks
    const int row = r0 + lc;
    bf16x8 rf0 = *(const bf16x8*)(ybf + (nb + row) * CF + g * 8);
    bf16x8 rf1 = *(const bf16x8*)(ybf + (nb + row) * CF + 32 + g * 8);
    const float sqr = sq[nb + row];

    u32 lst[8];
#pragma unroll
    for (int q = 0; q < 8; ++q) lst[q] = 0xFFFFFFFFu;

    const f32x4 zro = {0.f, 0.f, 0.f, 0.f};
    const int c0 = w * 1024;
    const size_t cb = (nb + c0 + lc) * CF + (size_t)g * 8;

    bf16x8 na0 = *(const bf16x8*)(ybf + cb);
    bf16x8 na1 = *(const bf16x8*)(ybf + cb + 32);
    for (int ct = 0; ct < 64; ++ct) {
        bf16x8 a0 = na0, a1 = na1;
        if (ct < 63) {
            size_t nxt = cb + (size_t)(ct + 1) * 16 * CF;
            na0 = *(const bf16x8*)(ybf + nxt);
            na1 = *(const bf16x8*)(ybf + nxt + 32);
        }
        const int cbase = c0 + ct * 16;
        float4 sc = *(const float4*)&sq[nb + cbase + g * 4];
        float scv[4] = {sc.x, sc.y, sc.z, sc.w};
        f32x4 acc = __builtin_amdgcn_mfma_f32_16x16x32_bf16(a0, rf0, zro, 0, 0, 0);
        acc = __builtin_amdgcn_mfma_f32_16x16x32_bf16(a1, rf1, acc, 0, 0, 0);
#pragma unroll
        for (int r = 0; r < 4; ++r) {
            float d2a = fmaxf((sqr + scv[r]) - 2.f * acc[r], 0.f);
            u32 key = (__float_as_uint(d2a) & 0xFFFFFF00u) | (u32)(ct * 4 + r);
            if (key < lst[7]) insertM32<8>(lst, key);
        }
    }

    // dump per-lane lists: row = lc, src = w*4+g
#pragma unroll
    for (int q = 0; q < 8; ++q)
        mlds[lc * 129 + (w * 4 + g) * 8 + q] = lst[q];
    __syncthreads();

    // phase M: 4 threads/row, each merges 4 sources -> top-8 (trunc-key + col order)
    if (tid < 64) {
        const int mrow = tid >> 2, s4 = tid & 3;
        u64 top8[8];
#pragma unroll
        for (int q = 0; q < 8; ++q) top8[q] = ~0ull;
#pragma unroll
        for (int s = 0; s < 4; ++s) {
            const int src = s4 * 4 + s;
            const u32 colhi = (src >> 2) * 1024 + (src & 3) * 4;
#pragma unroll
            for (int q = 0; q < 8; ++q) {
                u32 k = mlds[mrow * 129 + src * 8 + q];
                u32 idx8 = k & 0xFFu;
                u32 col = colhi + (idx8 >> 2) * 16 + (idx8 & 3);
                u64 mk = ((u64)(k & 0xFFFFFF00u) << 24) | col;
                if (mk < top8[7]) insertM64<8>(top8, mk);
            }
        }
#pragma unroll
        for (int q = 0; q < 8; ++q)
            cidx[mrow][s4 * 8 + q] = (u32)(top8[q] & 0xFFFu);
    }
    __syncthreads();

    // phase R: exact f32 rescore (trusted chain), 16 threads/row x 2 cands
    {
        const int rrow = tid >> 4, s = tid & 15;
        const float4* yr = (const float4*)(yf + (nb + r0 + rrow) * CF);
        const float sr = sq[nb + r0 + rrow];
#pragma unroll
        for (int j2 = 0; j2 < 2; ++j2) {
            const int q = s * 2 + j2;
            const u32 col = cidx[rrow][q];
            const float4* yc = (const float4*)(yf + (nb + col) * CF);
            float a = 0.f;
#pragma unroll
            for (int k = 0; k < 16; ++k) {
                float4 av = yr[k], bv = yc[k];
                a += av.x * bv.x;
                a += av.y * bv.y;
                a += av.z * bv.z;
                a += av.w * bv.w;
            }
            float d2 = (sr + sq[nb + col]) - 2.0f * a;
            float dd = sqrtf(fmaxf(d2, 0.0f));
            ckey[rrow][q] = ((u64)__float_as_uint(dd) << 32) | col;
        }
    }
    __syncthreads();

    // phase F: exact top-7 of 32 candidates -> cidx[row][0..6]
    if (tid < 16) {
        u64 t7[KNN];
#pragma unroll
        for (int q = 0; q < KNN; ++q) t7[q] = ~0ull;
#pragma unroll
        for (int q = 0; q < 32; ++q) {
            u64 k = ckey[tid][q];
            if (k < t7[KNN - 1]) insertM64<KNN>(t7, k);
        }
#pragma unroll
        for (int q = 0; q < KNN; ++q)
            cidx[tid][q] = (u32)(t7[q] & 0xFFFFFFFFu);
    }
    __syncthreads();

    // phase O: 7 ones per row (zeros pre-written by conv_fused_kernel)
    if (tid < 16 * KNN) {
        const int orow = tid / KNN, q = tid % KNN;
        u32 col = cidx[orow][q];
        adj[(nb + r0 + orow) * NN + col] = 1.0f;
    }
}

// ------------------------------------------------ launcher
extern "C" void kernel_launch(void* const* d_in, const int* in_sizes, int n_in,
                              void* d_out, int out_size, void* d_ws, size_t ws_size,
                              hipStream_t stream) {
    const float* x = (const float*)d_in[0];
    const float* w = (const float*)d_in[1];
    const float* bias = (const float*)d_in[2];

    float* y = (float*)d_out;                               // [4][4096][64]
    float* adj = (float*)d_out + (size_t)BATCH * NN * CF;   // [4][4096][4096]

    float* sq = (float*)d_ws;                               // 64 KB
    u16* ybf = (u16*)((char*)d_ws + 65536);                 // 2 MB bf16 features

    conv_fused_kernel<<<4096, 256, 0, stream>>>(x, w, bias, y, ybf, sq,
                                                (float4*)adj);
    screen_kernel<<<1024, 256, 0, stream>>>(ybf, y, sq, adj);
}